// Round 1
// baseline (220.978 us; speedup 1.0000x reference)
//
#include <hip/hip_runtime.h>

typedef _Float16 half8 __attribute__((ext_vector_type(8)));
typedef float floatx4 __attribute__((ext_vector_type(4)));

namespace {

constexpr int NODES = 512;   // nodes per graph
constexpr int DIM   = 256;   // latent dim
constexpr int BM    = 128;   // block tile (rows and cols)
constexpr int BK    = 32;    // K-step per LDS stage

// 2048 blocks = 128 graphs x 16 tiles; 256 threads = 4 waves; each wave does a
// 64x64 sub-tile as 4x4 mfma_f32_16x16x32_f16 accumulators.
__global__ __launch_bounds__(256, 3)
void decoder_kernel(const float* __restrict__ z, float* __restrict__ out) {
  __shared__ _Float16 As[BM * BK];
  __shared__ _Float16 Bs[BM * BK];

  const int bid  = blockIdx.x;
  const int g    = bid >> 4;       // graph id
  const int tile = bid & 15;
  const int tn   = tile >> 2;      // row-tile (n dim)
  const int tm   = tile & 3;       // col-tile (m dim)

  const int tid  = threadIdx.x;
  const int lane = tid & 63;
  const int wave = tid >> 6;
  const int wRow = wave >> 1;      // 0..1
  const int wCol = wave & 1;       // 0..1
  const int lrow = lane & 15;
  const int quad = lane >> 4;      // 0..3

  const float* zg = z + (size_t)g * NODES * DIM;
  const float* zA = zg + (size_t)tn * BM * DIM;   // rows for n side
  const float* zB = zg + (size_t)tm * BM * DIM;   // rows for m side

  floatx4 acc[4][4];
#pragma unroll
  for (int i = 0; i < 4; ++i)
#pragma unroll
    for (int j = 0; j < 4; ++j)
      acc[i][j] = (floatx4){0.f, 0.f, 0.f, 0.f};

  const int scol = (tid & 3) * 8;  // k-offset within BK handled by this thread

  for (int kk = 0; kk < DIM; kk += BK) {
    // --- stage 128x32 fp32 -> fp16 into LDS (both tiles), 8 k's per thread ---
#pragma unroll
    for (int it = 0; it < 2; ++it) {
      const int row = it * 64 + (tid >> 2);
      const float4* pa = reinterpret_cast<const float4*>(zA + row * DIM + kk + scol);
      const float4* pb = reinterpret_cast<const float4*>(zB + row * DIM + kk + scol);
      const float4 a0 = pa[0], a1 = pa[1];
      const float4 b0 = pb[0], b1 = pb[1];
      half8 ha, hb;
      ha[0] = (_Float16)a0.x; ha[1] = (_Float16)a0.y; ha[2] = (_Float16)a0.z; ha[3] = (_Float16)a0.w;
      ha[4] = (_Float16)a1.x; ha[5] = (_Float16)a1.y; ha[6] = (_Float16)a1.z; ha[7] = (_Float16)a1.w;
      hb[0] = (_Float16)b0.x; hb[1] = (_Float16)b0.y; hb[2] = (_Float16)b0.z; hb[3] = (_Float16)b0.w;
      hb[4] = (_Float16)b1.x; hb[5] = (_Float16)b1.y; hb[6] = (_Float16)b1.z; hb[7] = (_Float16)b1.w;
      *reinterpret_cast<half8*>(&As[row * BK + scol]) = ha;
      *reinterpret_cast<half8*>(&Bs[row * BK + scol]) = hb;
    }
    __syncthreads();

    // --- fragment loads (ds_read_b128) + 16 MFMAs ---
    half8 af[4], bf[4];
#pragma unroll
    for (int i = 0; i < 4; ++i)
      af[i] = *reinterpret_cast<const half8*>(&As[(wRow * 64 + i * 16 + lrow) * BK + quad * 8]);
#pragma unroll
    for (int j = 0; j < 4; ++j)
      bf[j] = *reinterpret_cast<const half8*>(&Bs[(wCol * 64 + j * 16 + lrow) * BK + quad * 8]);

#pragma unroll
    for (int i = 0; i < 4; ++i)
#pragma unroll
      for (int j = 0; j < 4; ++j)
        acc[i][j] = __builtin_amdgcn_mfma_f32_16x16x32_f16(af[i], bf[j], acc[i][j], 0, 0, 0);

    __syncthreads();
  }

  // --- epilogue: sigmoid + store fp32 ---
  float* outg = out + (size_t)g * NODES * NODES;
  const int nBase = tn * BM + wRow * 64;
  const int mBase = tm * BM + wCol * 64;
#pragma unroll
  for (int i = 0; i < 4; ++i) {
#pragma unroll
    for (int j = 0; j < 4; ++j) {
      const int m = mBase + j * 16 + lrow;
#pragma unroll
      for (int r = 0; r < 4; ++r) {
        const int n = nBase + i * 16 + quad * 4 + r;
        const float x = acc[i][j][r];
        outg[(size_t)n * NODES + m] = 1.0f / (1.0f + __expf(-x));
      }
    }
  }
}

} // namespace

extern "C" void kernel_launch(void* const* d_in, const int* in_sizes, int n_in,
                              void* d_out, int out_size, void* d_ws, size_t ws_size,
                              hipStream_t stream) {
  const float* z = (const float*)d_in[0];
  float* out = (float*)d_out;
  // 128 graphs x (4x4) 128x128 tiles of the 512x512 per-graph output
  dim3 grid(128 * 16);
  dim3 block(256);
  hipLaunchKernelGGL(decoder_kernel, grid, block, 0, stream, z, out);
}